// Round 8
// baseline (225.362 us; speedup 1.0000x reference)
//
#include <hip/hip_runtime.h>
#include <hip/hip_bf16.h>
#include <math.h>

#define N 8192
#define D 64
// fold (1/sqrt(D)) * log2(e) into Q so S2 = Qs·K is in base-2 units
#define QSCALE 0.18033688011112042f

typedef __attribute__((ext_vector_type(8))) short short8;
typedef __attribute__((ext_vector_type(16))) float f32x16;
typedef __attribute__((ext_vector_type(4))) float f32x4v;
typedef __attribute__((ext_vector_type(4))) unsigned int ui4;

__device__ inline short f32_to_bf16_bits(float x) {
    union { float f; unsigned u; } c; c.f = x;
    unsigned u = c.u;
    u += 0x7FFFu + ((u >> 16) & 1u);   // RNE
    return (short)(u >> 16);
}
__device__ inline float bfbits_to_f32(unsigned short u) {
    union { unsigned u; float f; } c; c.u = ((unsigned)u) << 16;
    return c.f;
}
__device__ inline unsigned cvt_pk_bf16(float a, float b) {
    __hip_bfloat162 h = __float22bfloat162_rn(make_float2(a, b));
    union { __hip_bfloat162 h; unsigned u; } c; c.h = h;
    return c.u;
}

// async global->LDS, 16B per lane, LDS dest = wave-uniform base + lane*16
#define GLDS(gp, lp)                                                            \
    __builtin_amdgcn_global_load_lds(                                           \
        (const __attribute__((address_space(1))) void*)(gp),                    \
        (__attribute__((address_space(3))) void*)(lp), 16, 0, 0)

// ---- fused prepass (identical to r7) ----
__global__ __launch_bounds__(256) void fa_conv(const float* __restrict__ q,
                                               const float* __restrict__ k,
                                               const float* __restrict__ v,
                                               short* __restrict__ Qb,
                                               short* __restrict__ Kp,
                                               short* __restrict__ Vp) {
    int bid = blockIdx.x, tid = threadIdx.x;
    if (bid < 512) {
        int i = (bid * 256 + tid) * 4;
        float4 a = *(const float4*)(q + i);
        unsigned lo = cvt_pk_bf16(a.x * QSCALE, a.y * QSCALE);
        unsigned hi = cvt_pk_bf16(a.z * QSCALE, a.w * QSCALE);
        unsigned long long u = (unsigned long long)lo | ((unsigned long long)hi << 32);
        *(unsigned long long*)(Qb + i) = u;
    } else if (bid < 768) {
        int t = bid - 512;
        int c = tid >> 6, l = tid & 63, ql = l & 31, hi = l >> 5;
        const float* src = k + (size_t)(t * 32 + ql) * D + c * 16 + hi * 8;
        float4 a = *(const float4*)(src);
        float4 b = *(const float4*)(src + 4);
        uint4 u = { cvt_pk_bf16(a.x, a.y), cvt_pk_bf16(a.z, a.w),
                    cvt_pk_bf16(b.x, b.y), cvt_pk_bf16(b.z, b.w) };
        *(uint4*)(Kp + (size_t)t * 2048 + c * 512 + l * 8) = u;
    } else {
        int t = bid - 768;
        int dt = tid >> 7, h = (tid >> 6) & 1, hi = (tid >> 5) & 1, ql = tid & 31;
        const float* src = v + (size_t)(t * 32 + h * 16 + hi * 8) * D + dt * 32 + ql;
        float f[8];
#pragma unroll
        for (int j = 0; j < 8; ++j) f[j] = src[(size_t)j * D];
        uint4 u = { cvt_pk_bf16(f[0], f[1]), cvt_pk_bf16(f[2], f[3]),
                    cvt_pk_bf16(f[4], f[5]), cvt_pk_bf16(f[6], f[7]) };
        *(uint4*)(Vp + (size_t)t * 2048 + dt * 1024 + h * 512 + hi * 256 + ql * 8) = u;
    }
}

// ---- main: identical to r7 ----
__global__ __launch_bounds__(256) void fa_part_kernel(const short* __restrict__ Qb,
                                                      const short* __restrict__ Kp,
                                                      const short* __restrict__ Vp,
                                                      short* __restrict__ OTb,
                                                      float* __restrict__ Ml,
                                                      int KN) {
    __shared__ short Klds[2][4096];
    __shared__ short Vlds[2][4096];

    const int qt = blockIdx.x & 63;
    const int s  = blockIdx.x >> 6;
    const int w = threadIdx.x >> 6, lane = threadIdx.x & 63;
    const int ql = lane & 31, hi = lane >> 5;
    const int qrow = qt * 128 + w * 32 + ql;

    const short* qp = Qb + (size_t)qrow * D + hi * 8;
    short8 qf0 = *(const short8*)(qp);
    short8 qf1 = *(const short8*)(qp + 16);
    short8 qf2 = *(const short8*)(qp + 32);
    short8 qf3 = *(const short8*)(qp + 48);

    f32x16 acc0 = {}, acc1 = {};
    float mex = -INFINITY, lsum = 0.f;

    const int T0 = (s * KN) >> 6, nt = KN >> 6;
    const short* kg = Kp + (size_t)T0 * 4096 + w * 512 + lane * 8;
    const short* vg = Vp + (size_t)T0 * 4096 + w * 512 + lane * 8;

#define STAGE(buf, T)                                                     \
    do {                                                                  \
        const short* kq = kg + (size_t)(T) * 4096;                        \
        const short* vq = vg + (size_t)(T) * 4096;                        \
        GLDS(kq,        &Klds[buf][w * 512]);                             \
        GLDS(kq + 2048, &Klds[buf][2048 + w * 512]);                      \
        GLDS(vq,        &Vlds[buf][w * 512]);                             \
        GLDS(vq + 2048, &Vlds[buf][2048 + w * 512]);                      \
    } while (0)

    STAGE(0, 0);
    asm volatile("s_waitcnt vmcnt(0)" ::: "memory");
    __syncthreads();

#pragma unroll 1
    for (int T = 0; T < nt; ++T) {
        const int cur = T & 1;
        if (T + 1 < nt) STAGE(cur ^ 1, T + 1);

#pragma unroll
        for (int u = 0; u < 2; ++u) {
            const short* kt = &Klds[cur][u * 2048];
            const short* vt = &Vlds[cur][u * 2048];
            short8 kf0  = *(const short8*)(kt + lane * 8);
            short8 kf1  = *(const short8*)(kt + 512 + lane * 8);
            short8 kf2  = *(const short8*)(kt + 1024 + lane * 8);
            short8 kf3  = *(const short8*)(kt + 1536 + lane * 8);
            short8 vf00 = *(const short8*)(vt + lane * 8);
            short8 vf01 = *(const short8*)(vt + 512 + lane * 8);
            short8 vf10 = *(const short8*)(vt + 1024 + lane * 8);
            short8 vf11 = *(const short8*)(vt + 1536 + lane * 8);

            f32x16 st = {};
            st = __builtin_amdgcn_mfma_f32_32x32x16_bf16(kf0, qf0, st, 0, 0, 0);
            st = __builtin_amdgcn_mfma_f32_32x32x16_bf16(kf1, qf1, st, 0, 0, 0);
            st = __builtin_amdgcn_mfma_f32_32x32x16_bf16(kf2, qf2, st, 0, 0, 0);
            st = __builtin_amdgcn_mfma_f32_32x32x16_bf16(kf3, qf3, st, 0, 0, 0);

            float g0 = fmaxf(fmaxf(st[0], st[1]), st[2]);
            float g1 = fmaxf(fmaxf(st[3], st[4]), st[5]);
            float g2 = fmaxf(fmaxf(st[6], st[7]), st[8]);
            float g3 = fmaxf(fmaxf(st[9], st[10]), st[11]);
            float g4 = fmaxf(fmaxf(st[12], st[13]), st[14]);
            float t5 = fmaxf(fmaxf(g0, g1), g2);
            float t6 = fmaxf(fmaxf(g3, g4), st[15]);
            mex = fmaxf(mex, fmaxf(t5, t6));

            unsigned pk0, pk1, pk2, pk3, pk4, pk5, pk6, pk7;
            float rs;
            {
                float a, b;
                a = __builtin_amdgcn_exp2f(st[0]);  b = __builtin_amdgcn_exp2f(st[1]);
                rs = a + b;            pk0 = cvt_pk_bf16(a, b);
                a = __builtin_amdgcn_exp2f(st[2]);  b = __builtin_amdgcn_exp2f(st[3]);
                rs += a + b;           pk1 = cvt_pk_bf16(a, b);
                a = __builtin_amdgcn_exp2f(st[4]);  b = __builtin_amdgcn_exp2f(st[5]);
                rs += a + b;           pk2 = cvt_pk_bf16(a, b);
                a = __builtin_amdgcn_exp2f(st[6]);  b = __builtin_amdgcn_exp2f(st[7]);
                rs += a + b;           pk3 = cvt_pk_bf16(a, b);
                a = __builtin_amdgcn_exp2f(st[8]);  b = __builtin_amdgcn_exp2f(st[9]);
                rs += a + b;           pk4 = cvt_pk_bf16(a, b);
                a = __builtin_amdgcn_exp2f(st[10]); b = __builtin_amdgcn_exp2f(st[11]);
                rs += a + b;           pk5 = cvt_pk_bf16(a, b);
                a = __builtin_amdgcn_exp2f(st[12]); b = __builtin_amdgcn_exp2f(st[13]);
                rs += a + b;           pk6 = cvt_pk_bf16(a, b);
                a = __builtin_amdgcn_exp2f(st[14]); b = __builtin_amdgcn_exp2f(st[15]);
                rs += a + b;           pk7 = cvt_pk_bf16(a, b);
            }
            lsum += rs;

            auto r0 = __builtin_amdgcn_permlane32_swap((int)pk0, (int)pk2, false, false);
            auto r1 = __builtin_amdgcn_permlane32_swap((int)pk1, (int)pk3, false, false);
            auto r2 = __builtin_amdgcn_permlane32_swap((int)pk4, (int)pk6, false, false);
            auto r3 = __builtin_amdgcn_permlane32_swap((int)pk5, (int)pk7, false, false);
            union { int i[4]; short8 s8; } pb0, pb1;
            pb0.i[0] = r0[0]; pb0.i[1] = r1[0]; pb0.i[2] = r0[1]; pb0.i[3] = r1[1];
            pb1.i[0] = r2[0]; pb1.i[1] = r3[0]; pb1.i[2] = r2[1]; pb1.i[3] = r3[1];

            acc0 = __builtin_amdgcn_mfma_f32_32x32x16_bf16(vf00, pb0.s8, acc0, 0, 0, 0);
            acc0 = __builtin_amdgcn_mfma_f32_32x32x16_bf16(vf01, pb1.s8, acc0, 0, 0, 0);
            acc1 = __builtin_amdgcn_mfma_f32_32x32x16_bf16(vf10, pb0.s8, acc1, 0, 0, 0);
            acc1 = __builtin_amdgcn_mfma_f32_32x32x16_bf16(vf11, pb1.s8, acc1, 0, 0, 0);
        }

        asm volatile("s_waitcnt vmcnt(0)" ::: "memory");
        __syncthreads();
    }
#undef STAGE

    mex = fmaxf(mex, __shfl_xor(mex, 32));
    lsum += __shfl_xor(lsum, 32);

#pragma unroll
    for (int r = 0; r < 16; ++r) {
        int d0 = (r & 3) + 8 * (r >> 2) + 4 * hi;
        OTb[(size_t)(s * 64 + d0) * N + qrow]      = f32_to_bf16_bits(acc0[r]);
        OTb[(size_t)(s * 64 + 32 + d0) * N + qrow] = f32_to_bf16_bits(acc1[r]);
    }
    if (hi == 0) {
        Ml[(size_t)(s * 2 + 0) * N + qrow] = lsum;
        Ml[(size_t)(s * 2 + 1) * N + qrow] = mex;
    }
}

// ---- DIAGNOSTIC kernels (write to scratch; not validated) ----
// VAR 0: loads + QK^T MFMA + PV MFMA only (P = bit-alias of st; no softmax)
// VAR 1: + full softmax (max, exp2, cvt_pk, rowsum); NO permlane redistribute
template<int VAR, int REPS>
__global__ __launch_bounds__(256) void fa_diag(const short* __restrict__ Qb,
                                               const short* __restrict__ Kp,
                                               const short* __restrict__ Vp,
                                               short* __restrict__ OTb2,
                                               float* __restrict__ Ml2,
                                               int KN) {
    __shared__ short Klds[2][4096];
    __shared__ short Vlds[2][4096];

    const int qt = blockIdx.x & 63;
    const int s  = blockIdx.x >> 6;
    const int w = threadIdx.x >> 6, lane = threadIdx.x & 63;
    const int ql = lane & 31, hi = lane >> 5;
    const int qrow = qt * 128 + w * 32 + ql;

    const short* qp = Qb + (size_t)qrow * D + hi * 8;
    short8 qf0 = *(const short8*)(qp);
    short8 qf1 = *(const short8*)(qp + 16);
    short8 qf2 = *(const short8*)(qp + 32);
    short8 qf3 = *(const short8*)(qp + 48);

    f32x16 acc0 = {}, acc1 = {};
    float mex = -INFINITY, lsum = 0.f;

    const int T0 = (s * KN) >> 6, nt = KN >> 6;
    const short* kg = Kp + (size_t)T0 * 4096 + w * 512 + lane * 8;
    const short* vg = Vp + (size_t)T0 * 4096 + w * 512 + lane * 8;

#define STAGE(buf, T)                                                     \
    do {                                                                  \
        const short* kq = kg + (size_t)(T) * 4096;                        \
        const short* vq = vg + (size_t)(T) * 4096;                        \
        GLDS(kq,        &Klds[buf][w * 512]);                             \
        GLDS(kq + 2048, &Klds[buf][2048 + w * 512]);                      \
        GLDS(vq,        &Vlds[buf][w * 512]);                             \
        GLDS(vq + 2048, &Vlds[buf][2048 + w * 512]);                      \
    } while (0)

#pragma unroll 1
    for (int rep = 0; rep < REPS; ++rep) {
        STAGE(0, 0);
        asm volatile("s_waitcnt vmcnt(0)" ::: "memory");
        __syncthreads();

#pragma unroll 1
        for (int T = 0; T < nt; ++T) {
            const int cur = T & 1;
            if (T + 1 < nt) STAGE(cur ^ 1, T + 1);

#pragma unroll
            for (int u = 0; u < 2; ++u) {
                const short* kt = &Klds[cur][u * 2048];
                const short* vt = &Vlds[cur][u * 2048];
                short8 kf0  = *(const short8*)(kt + lane * 8);
                short8 kf1  = *(const short8*)(kt + 512 + lane * 8);
                short8 kf2  = *(const short8*)(kt + 1024 + lane * 8);
                short8 kf3  = *(const short8*)(kt + 1536 + lane * 8);
                short8 vf00 = *(const short8*)(vt + lane * 8);
                short8 vf01 = *(const short8*)(vt + 512 + lane * 8);
                short8 vf10 = *(const short8*)(vt + 1024 + lane * 8);
                short8 vf11 = *(const short8*)(vt + 1536 + lane * 8);

                f32x16 st = {};
                st = __builtin_amdgcn_mfma_f32_32x32x16_bf16(kf0, qf0, st, 0, 0, 0);
                st = __builtin_amdgcn_mfma_f32_32x32x16_bf16(kf1, qf1, st, 0, 0, 0);
                st = __builtin_amdgcn_mfma_f32_32x32x16_bf16(kf2, qf2, st, 0, 0, 0);
                st = __builtin_amdgcn_mfma_f32_32x32x16_bf16(kf3, qf3, st, 0, 0, 0);

                short8 pb0s, pb1s;
                if constexpr (VAR == 0) {
                    f32x4v lo4 = __builtin_shufflevector(st, st, 0, 1, 2, 3);
                    f32x4v hi4 = __builtin_shufflevector(st, st, 4, 5, 6, 7);
                    pb0s = __builtin_bit_cast(short8, lo4);
                    pb1s = __builtin_bit_cast(short8, hi4);
                } else {
                    float g0 = fmaxf(fmaxf(st[0], st[1]), st[2]);
                    float g1 = fmaxf(fmaxf(st[3], st[4]), st[5]);
                    float g2 = fmaxf(fmaxf(st[6], st[7]), st[8]);
                    float g3 = fmaxf(fmaxf(st[9], st[10]), st[11]);
                    float g4 = fmaxf(fmaxf(st[12], st[13]), st[14]);
                    float t5 = fmaxf(fmaxf(g0, g1), g2);
                    float t6 = fmaxf(fmaxf(g3, g4), st[15]);
                    mex = fmaxf(mex, fmaxf(t5, t6));

                    unsigned pk0, pk1, pk2, pk3, pk4, pk5, pk6, pk7;
                    float rs;
                    {
                        float a, b;
                        a = __builtin_amdgcn_exp2f(st[0]);  b = __builtin_amdgcn_exp2f(st[1]);
                        rs = a + b;            pk0 = cvt_pk_bf16(a, b);
                        a = __builtin_amdgcn_exp2f(st[2]);  b = __builtin_amdgcn_exp2f(st[3]);
                        rs += a + b;           pk1 = cvt_pk_bf16(a, b);
                        a = __builtin_amdgcn_exp2f(st[4]);  b = __builtin_amdgcn_exp2f(st[5]);
                        rs += a + b;           pk2 = cvt_pk_bf16(a, b);
                        a = __builtin_amdgcn_exp2f(st[6]);  b = __builtin_amdgcn_exp2f(st[7]);
                        rs += a + b;           pk3 = cvt_pk_bf16(a, b);
                        a = __builtin_amdgcn_exp2f(st[8]);  b = __builtin_amdgcn_exp2f(st[9]);
                        rs += a + b;           pk4 = cvt_pk_bf16(a, b);
                        a = __builtin_amdgcn_exp2f(st[10]); b = __builtin_amdgcn_exp2f(st[11]);
                        rs += a + b;           pk5 = cvt_pk_bf16(a, b);
                        a = __builtin_amdgcn_exp2f(st[12]); b = __builtin_amdgcn_exp2f(st[13]);
                        rs += a + b;           pk6 = cvt_pk_bf16(a, b);
                        a = __builtin_amdgcn_exp2f(st[14]); b = __builtin_amdgcn_exp2f(st[15]);
                        rs += a + b;           pk7 = cvt_pk_bf16(a, b);
                    }
                    lsum += rs;
                    ui4 ua = { pk0, pk1, pk2, pk3 };
                    ui4 ub = { pk4, pk5, pk6, pk7 };
                    pb0s = __builtin_bit_cast(short8, ua);
                    pb1s = __builtin_bit_cast(short8, ub);
                }

                acc0 = __builtin_amdgcn_mfma_f32_32x32x16_bf16(vf00, pb0s, acc0, 0, 0, 0);
                acc0 = __builtin_amdgcn_mfma_f32_32x32x16_bf16(vf01, pb1s, acc0, 0, 0, 0);
                acc1 = __builtin_amdgcn_mfma_f32_32x32x16_bf16(vf10, pb0s, acc1, 0, 0, 0);
                acc1 = __builtin_amdgcn_mfma_f32_32x32x16_bf16(vf11, pb1s, acc1, 0, 0, 0);
            }

            asm volatile("s_waitcnt vmcnt(0)" ::: "memory");
            __syncthreads();
        }
    }
#undef STAGE

    if constexpr (VAR == 0) { mex = acc0[0]; lsum = acc0[1]; }
    mex = fmaxf(mex, __shfl_xor(mex, 32));
    lsum += __shfl_xor(lsum, 32);

#pragma unroll
    for (int r = 0; r < 16; ++r) {
        int d0 = (r & 3) + 8 * (r >> 2) + 4 * hi;
        OTb2[(size_t)(s * 64 + d0) * N + qrow]      = f32_to_bf16_bits(acc0[r]);
        OTb2[(size_t)(s * 64 + 32 + d0) * N + qrow] = f32_to_bf16_bits(acc1[r]);
    }
    if (hi == 0) {
        Ml2[(size_t)(s * 2 + 0) * N + qrow] = lsum;
        Ml2[(size_t)(s * 2 + 1) * N + qrow] = mex;
    }
}

// ---- combine (identical to r7) ----
__global__ __launch_bounds__(256) void fa_comb_kernel(const short* __restrict__ OTb,
                                                      const float* __restrict__ Ml,
                                                      float* __restrict__ Out, int S) {
    const int r0 = blockIdx.x * 64;
    const int row = threadIdx.x & 63, db = threadIdx.x >> 6;
    const int grow = r0 + row;

    float v[16];
#pragma unroll
    for (int i = 0; i < 16; ++i) v[i] = 0.f;
    float L = 0.f, mg = -INFINITY;
    for (int s = 0; s < S; ++s) {
#pragma unroll
        for (int i = 0; i < 16; ++i)
            v[i] += bfbits_to_f32((unsigned short)OTb[(size_t)(s * 64 + db * 16 + i) * N + grow]);
        L  += Ml[(size_t)(s * 2 + 0) * N + grow];
        mg = fmaxf(mg, Ml[(size_t)(s * 2 + 1) * N + grow]);
    }
    float inv = 1.0f / L;
    float4* outv = (float4*)(Out + (size_t)grow * D + db * 16);
#pragma unroll
    for (int i4 = 0; i4 < 4; ++i4) {
        float4 o = { v[i4 * 4 + 0] * inv, v[i4 * 4 + 1] * inv,
                     v[i4 * 4 + 2] * inv, v[i4 * 4 + 3] * inv };
        outv[i4] = o;
    }
    if (db == 0) Out[(size_t)N * D + grow] = exp2f(-mg) * L;
}

extern "C" void kernel_launch(void* const* d_in, const int* in_sizes, int n_in,
                              void* d_out, int out_size, void* d_ws, size_t ws_size,
                              hipStream_t stream) {
    const float* q = (const float*)d_in[0];
    const float* k = (const float*)d_in[1];
    const float* v = (const float*)d_in[2];
    float* out = (float*)d_out;

    short* Qb = (short*)d_ws;                         // 1 MB
    short* Kp = Qb + (size_t)N * D;                   // 1 MB
    short* Vp = Kp + (size_t)N * D;                   // 1 MB
    short* OTb = (short*)((char*)d_ws + 3 * 1048576);

    int S = 16;
    while (S > 1 &&
           3ull * 1048576 + 2 * ((size_t)S * (64ull * N * 2) + (size_t)S * (2ull * N * 4)) > ws_size)
        S >>= 1;
    float* Ml = (float*)(OTb + (size_t)S * 64 * N);
    short* OTb2 = (short*)(Ml + (size_t)S * 2 * N);
    float* Ml2 = (float*)(OTb2 + (size_t)S * 64 * N);
    int KN = N / S;

    fa_conv<<<1024, 256, 0, stream>>>(q, k, v, Qb, Kp, Vp);
    fa_part_kernel<<<64 * S, 256, 0, stream>>>(Qb, Kp, Vp, OTb, Ml, KN);
    fa_comb_kernel<<<N / 64, 256, 0, stream>>>(OTb, Ml, out, S);
    // diagnostics (scratch-only, not validated): phase-cost ablation
    fa_diag<0, 6><<<64 * S, 256, 0, stream>>>(Qb, Kp, Vp, OTb2, Ml2, KN);
    fa_diag<1, 4><<<64 * S, 256, 0, stream>>>(Qb, Kp, Vp, OTb2, Ml2, KN);
}

// Round 9
// 48.609 us; speedup vs baseline: 4.6362x; 4.6362x over previous
//
#include <hip/hip_runtime.h>
#include <hip/hip_bf16.h>
#include <math.h>

#define N 8192
#define D 64
// fold (1/sqrt(D)) * log2(e) into Q so S2 = Qs·K is in base-2 units
#define QSCALE 0.18033688011112042f

typedef __attribute__((ext_vector_type(8))) short short8;
typedef __attribute__((ext_vector_type(16))) float f32x16;

__device__ inline short f32_to_bf16_bits(float x) {
    union { float f; unsigned u; } c; c.f = x;
    unsigned u = c.u;
    u += 0x7FFFu + ((u >> 16) & 1u);   // RNE
    return (short)(u >> 16);
}
__device__ inline float bfbits_to_f32(unsigned short u) {
    union { unsigned u; float f; } c; c.u = ((unsigned)u) << 16;
    return c.f;
}
__device__ inline unsigned cvt_pk_bf16(float a, float b) {
    __hip_bfloat162 h = __float22bfloat162_rn(make_float2(a, b));
    union { __hip_bfloat162 h; unsigned u; } c; c.h = h;
    return c.u;
}
__device__ inline float max3f(float a, float b, float c) {
    float d;
    asm("v_max3_f32 %0, %1, %2, %3" : "=v"(d) : "v"(a), "v"(b), "v"(c));
    return d;
}

// ---- fused prepass (identical to r7) ----
// blocks [0,512): Q scaled -> bf16 rows
// blocks [512,768): K -> fragment-ordered Kp[t][c][lane][8]
// blocks [768,1024): V -> fragment-ordered Vp[t][dt][h][lane][8]
__global__ __launch_bounds__(256) void fa_conv(const float* __restrict__ q,
                                               const float* __restrict__ k,
                                               const float* __restrict__ v,
                                               short* __restrict__ Qb,
                                               short* __restrict__ Kp,
                                               short* __restrict__ Vp) {
    int bid = blockIdx.x, tid = threadIdx.x;
    if (bid < 512) {
        int i = (bid * 256 + tid) * 4;
        float4 a = *(const float4*)(q + i);
        unsigned lo = cvt_pk_bf16(a.x * QSCALE, a.y * QSCALE);
        unsigned hi = cvt_pk_bf16(a.z * QSCALE, a.w * QSCALE);
        unsigned long long u = (unsigned long long)lo | ((unsigned long long)hi << 32);
        *(unsigned long long*)(Qb + i) = u;
    } else if (bid < 768) {
        int t = bid - 512;
        int c = tid >> 6, l = tid & 63, ql = l & 31, hi = l >> 5;
        const float* src = k + (size_t)(t * 32 + ql) * D + c * 16 + hi * 8;
        float4 a = *(const float4*)(src);
        float4 b = *(const float4*)(src + 4);
        uint4 u = { cvt_pk_bf16(a.x, a.y), cvt_pk_bf16(a.z, a.w),
                    cvt_pk_bf16(b.x, b.y), cvt_pk_bf16(b.z, b.w) };
        *(uint4*)(Kp + (size_t)t * 2048 + c * 512 + l * 8) = u;
    } else {
        int t = bid - 768;
        int dt = tid >> 7, h = (tid >> 6) & 1, hi = (tid >> 5) & 1, ql = tid & 31;
        const float* src = v + (size_t)(t * 32 + h * 16 + hi * 8) * D + dt * 32 + ql;
        float f[8];
#pragma unroll
        for (int j = 0; j < 8; ++j) f[j] = src[(size_t)j * D];
        uint4 u = { cvt_pk_bf16(f[0], f[1]), cvt_pk_bf16(f[2], f[3]),
                    cvt_pk_bf16(f[4], f[5]), cvt_pk_bf16(f[6], f[7]) };
        *(uint4*)(Vp + (size_t)t * 2048 + dt * 1024 + h * 512 + hi * 256 + ql * 8) = u;
    }
}

// ---- main: 32x32 swapped-operand FA partials ----
// No LDS, no barriers. K register-double-buffered one tile ahead; V loaded at
// tile start, consumed ~400cy later at PV (L2-hit latency fully covered).
__global__ __launch_bounds__(256) void fa_part_kernel(const short* __restrict__ Qb,
                                                      const short* __restrict__ Kp,
                                                      const short* __restrict__ Vp,
                                                      short* __restrict__ OTb,
                                                      float* __restrict__ Ml,
                                                      int KN) {
    const int qt = blockIdx.x & 63;
    const int s  = blockIdx.x >> 6;
    const int w = threadIdx.x >> 6, lane = threadIdx.x & 63;
    const int ql = lane & 31, hi = lane >> 5;
    const int qrow = qt * 128 + w * 32 + ql;

    const short* qp = Qb + (size_t)qrow * D + hi * 8;
    short8 qf0 = *(const short8*)(qp);
    short8 qf1 = *(const short8*)(qp + 16);
    short8 qf2 = *(const short8*)(qp + 32);
    short8 qf3 = *(const short8*)(qp + 48);

    f32x16 acc0 = {}, acc1 = {};
    float mex = -INFINITY, lsum = 0.f;

    const int t0 = (s * KN) >> 5, nt = KN >> 5;   // 32-key tiles
    const short* kbp = Kp + (size_t)t0 * 2048 + lane * 8;
    const short* vbp = Vp + (size_t)t0 * 2048 + lane * 8;

    short8 kA0, kA1, kA2, kA3, kB0, kB1, kB2, kB3;
    short8 vf0, vf1, vf2, vf3;

#define LOADK(d0, d1, d2, d3, tt) do {                                     \
        const short* p_ = kbp + (size_t)(tt) * 2048;                       \
        d0 = *(const short8*)(p_);                                         \
        d1 = *(const short8*)(p_ + 512);                                   \
        d2 = *(const short8*)(p_ + 1024);                                  \
        d3 = *(const short8*)(p_ + 1536);                                  \
    } while (0)
#define LOADV(tt) do {                                                     \
        const short* p_ = vbp + (size_t)(tt) * 2048;                       \
        vf0 = *(const short8*)(p_);                                        \
        vf1 = *(const short8*)(p_ + 512);                                  \
        vf2 = *(const short8*)(p_ + 1024);                                 \
        vf3 = *(const short8*)(p_ + 1536);                                 \
    } while (0)

    // One 32-key tile: QK^T -> max3 tree -> exp2+pack+rowsum -> permlane -> PV
#define TILE(K0, K1, K2, K3) do {                                           \
        __builtin_amdgcn_s_setprio(1);                                      \
        f32x16 st = {};                                                     \
        st = __builtin_amdgcn_mfma_f32_32x32x16_bf16(K0, qf0, st, 0, 0, 0); \
        st = __builtin_amdgcn_mfma_f32_32x32x16_bf16(K1, qf1, st, 0, 0, 0); \
        st = __builtin_amdgcn_mfma_f32_32x32x16_bf16(K2, qf2, st, 0, 0, 0); \
        st = __builtin_amdgcn_mfma_f32_32x32x16_bf16(K3, qf3, st, 0, 0, 0); \
        __builtin_amdgcn_s_setprio(0);                                      \
        float m0_ = max3f(st[0], st[1], st[2]);                             \
        float m1_ = max3f(st[3], st[4], st[5]);                             \
        float m2_ = max3f(st[6], st[7], st[8]);                             \
        float m3_ = max3f(st[9], st[10], st[11]);                           \
        float m4_ = max3f(st[12], st[13], st[14]);                          \
        mex = max3f(mex, max3f(m0_, m1_, m2_), max3f(m3_, m4_, st[15]));    \
        unsigned pk0, pk1, pk2, pk3, pk4, pk5, pk6, pk7;                    \
        float rs_;                                                          \
        {                                                                   \
            float a_, b_;                                                   \
            a_ = __builtin_amdgcn_exp2f(st[0]);  b_ = __builtin_amdgcn_exp2f(st[1]);  \
            rs_ = a_ + b_;         pk0 = cvt_pk_bf16(a_, b_);               \
            a_ = __builtin_amdgcn_exp2f(st[2]);  b_ = __builtin_amdgcn_exp2f(st[3]);  \
            rs_ += a_ + b_;        pk1 = cvt_pk_bf16(a_, b_);               \
            a_ = __builtin_amdgcn_exp2f(st[4]);  b_ = __builtin_amdgcn_exp2f(st[5]);  \
            rs_ += a_ + b_;        pk2 = cvt_pk_bf16(a_, b_);               \
            a_ = __builtin_amdgcn_exp2f(st[6]);  b_ = __builtin_amdgcn_exp2f(st[7]);  \
            rs_ += a_ + b_;        pk3 = cvt_pk_bf16(a_, b_);               \
            a_ = __builtin_amdgcn_exp2f(st[8]);  b_ = __builtin_amdgcn_exp2f(st[9]);  \
            rs_ += a_ + b_;        pk4 = cvt_pk_bf16(a_, b_);               \
            a_ = __builtin_amdgcn_exp2f(st[10]); b_ = __builtin_amdgcn_exp2f(st[11]); \
            rs_ += a_ + b_;        pk5 = cvt_pk_bf16(a_, b_);               \
            a_ = __builtin_amdgcn_exp2f(st[12]); b_ = __builtin_amdgcn_exp2f(st[13]); \
            rs_ += a_ + b_;        pk6 = cvt_pk_bf16(a_, b_);               \
            a_ = __builtin_amdgcn_exp2f(st[14]); b_ = __builtin_amdgcn_exp2f(st[15]); \
            rs_ += a_ + b_;        pk7 = cvt_pk_bf16(a_, b_);               \
        }                                                                   \
        lsum += rs_;                                                        \
        auto r0_ = __builtin_amdgcn_permlane32_swap((int)pk0, (int)pk2, false, false); \
        auto r1_ = __builtin_amdgcn_permlane32_swap((int)pk1, (int)pk3, false, false); \
        auto r2_ = __builtin_amdgcn_permlane32_swap((int)pk4, (int)pk6, false, false); \
        auto r3_ = __builtin_amdgcn_permlane32_swap((int)pk5, (int)pk7, false, false); \
        union { int i[4]; short8 s8; } pb0, pb1;                            \
        pb0.i[0] = r0_[0]; pb0.i[1] = r1_[0]; pb0.i[2] = r0_[1]; pb0.i[3] = r1_[1]; \
        pb1.i[0] = r2_[0]; pb1.i[1] = r3_[0]; pb1.i[2] = r2_[1]; pb1.i[3] = r3_[1]; \
        __builtin_amdgcn_s_setprio(1);                                      \
        acc0 = __builtin_amdgcn_mfma_f32_32x32x16_bf16(vf0, pb0.s8, acc0, 0, 0, 0); \
        acc0 = __builtin_amdgcn_mfma_f32_32x32x16_bf16(vf1, pb1.s8, acc0, 0, 0, 0); \
        acc1 = __builtin_amdgcn_mfma_f32_32x32x16_bf16(vf2, pb0.s8, acc1, 0, 0, 0); \
        acc1 = __builtin_amdgcn_mfma_f32_32x32x16_bf16(vf3, pb1.s8, acc1, 0, 0, 0); \
        __builtin_amdgcn_s_setprio(0);                                      \
    } while (0)

    LOADK(kA0, kA1, kA2, kA3, 0);
#pragma unroll 1
    for (int T = 0; T < nt; T += 2) {
        LOADV(T);                                   // V for tile T (used at PV-A)
        LOADK(kB0, kB1, kB2, kB3, T + 1);           // K one tile ahead
        TILE(kA0, kA1, kA2, kA3);
        LOADV(T + 1);                               // V for tile T+1
        if (T + 2 < nt) LOADK(kA0, kA1, kA2, kA3, T + 2);
        TILE(kB0, kB1, kB2, kB3);
    }
#undef LOADK
#undef LOADV
#undef TILE

    // cross-half reductions (lane's 16 k-rows + partner's 16 = full 32 per q)
    mex = fmaxf(mex, __shfl_xor(mex, 32));
    lsum += __shfl_xor(lsum, 32);

    // write O^T partials (bf16): OTb[s*64+d][qrow]
#pragma unroll
    for (int r = 0; r < 16; ++r) {
        int d0 = (r & 3) + 8 * (r >> 2) + 4 * hi;
        OTb[(size_t)(s * 64 + d0) * N + qrow]      = f32_to_bf16_bits(acc0[r]);
        OTb[(size_t)(s * 64 + 32 + d0) * N + qrow] = f32_to_bf16_bits(acc1[r]);
    }
    if (hi == 0) {
        Ml[(size_t)(s * 2 + 0) * N + qrow] = lsum;
        Ml[(size_t)(s * 2 + 1) * N + qrow] = mex;
    }
}

// ---- combine: plain sum of partials, L = exp2(-mg)*sum(l) ----
__global__ __launch_bounds__(256) void fa_comb_kernel(const short* __restrict__ OTb,
                                                      const float* __restrict__ Ml,
                                                      float* __restrict__ Out, int S) {
    const int r0 = blockIdx.x * 64;
    const int row = threadIdx.x & 63, db = threadIdx.x >> 6;
    const int grow = r0 + row;

    float v[16];
#pragma unroll
    for (int i = 0; i < 16; ++i) v[i] = 0.f;
    float L = 0.f, mg = -INFINITY;
    for (int s = 0; s < S; ++s) {
#pragma unroll
        for (int i = 0; i < 16; ++i)
            v[i] += bfbits_to_f32((unsigned short)OTb[(size_t)(s * 64 + db * 16 + i) * N + grow]);
        L  += Ml[(size_t)(s * 2 + 0) * N + grow];
        mg = fmaxf(mg, Ml[(size_t)(s * 2 + 1) * N + grow]);
    }
    float inv = 1.0f / L;
    float4* outv = (float4*)(Out + (size_t)grow * D + db * 16);
#pragma unroll
    for (int i4 = 0; i4 < 4; ++i4) {
        float4 o = { v[i4 * 4 + 0] * inv, v[i4 * 4 + 1] * inv,
                     v[i4 * 4 + 2] * inv, v[i4 * 4 + 3] * inv };
        outv[i4] = o;
    }
    if (db == 0) Out[(size_t)N * D + grow] = exp2f(-mg) * L;
}

extern "C" void kernel_launch(void* const* d_in, const int* in_sizes, int n_in,
                              void* d_out, int out_size, void* d_ws, size_t ws_size,
                              hipStream_t stream) {
    const float* q = (const float*)d_in[0];
    const float* k = (const float*)d_in[1];
    const float* v = (const float*)d_in[2];
    float* out = (float*)d_out;

    short* Qb = (short*)d_ws;                         // 1 MB
    short* Kp = Qb + (size_t)N * D;                   // 1 MB
    short* Vp = Kp + (size_t)N * D;                   // 1 MB
    short* OTb = (short*)((char*)d_ws + 3 * 1048576); // S*64*N bf16

    int S = 16;
    while (S > 1 &&
           3ull * 1048576 + (size_t)S * (64ull * N * 2) + (size_t)S * (2ull * N * 4) > ws_size)
        S >>= 1;
    float* Ml = (float*)(OTb + (size_t)S * 64 * N);
    int KN = N / S;

    fa_conv<<<1024, 256, 0, stream>>>(q, k, v, Qb, Kp, Vp);
    fa_part_kernel<<<64 * S, 256, 0, stream>>>(Qb, Kp, Vp, OTb, Ml, KN);
    fa_comb_kernel<<<N / 64, 256, 0, stream>>>(OTb, Ml, out, S);
}

// Round 11
// 47.538 us; speedup vs baseline: 4.7407x; 1.0225x over previous
//
#include <hip/hip_runtime.h>
#include <hip/hip_bf16.h>
#include <math.h>

#define N 8192
#define D 64
// fold (1/sqrt(D)) * log2(e) into Q so S2 = Qs·K is in base-2 units
#define QSCALE 0.18033688011112042f

typedef __attribute__((ext_vector_type(8))) short short8;
typedef __attribute__((ext_vector_type(16))) float f32x16;
typedef __attribute__((ext_vector_type(4))) unsigned int ui4;

__device__ inline short f32_to_bf16_bits(float x) {
    unsigned u = __builtin_bit_cast(unsigned, x);
    u += 0x7FFFu + ((u >> 16) & 1u);   // RNE
    return (short)(u >> 16);
}
__device__ inline float bfbits_to_f32(unsigned short u) {
    return __builtin_bit_cast(float, ((unsigned)u) << 16);
}
// v_cvt_pk_bf16_f32: packs two f32 -> two bf16 (RNE) in one VALU op.
// No builtin on gfx950 (m240) -> inline asm.
__device__ inline unsigned cvt_pk_bf16(float a, float b) {
    unsigned r;
    asm("v_cvt_pk_bf16_f32 %0, %1, %2" : "=v"(r) : "v"(a), "v"(b));
    return r;
}
__device__ inline float max3f(float a, float b, float c) {
    float d;
    asm("v_max3_f32 %0, %1, %2, %3" : "=v"(d) : "v"(a), "v"(b), "v"(c));
    return d;
}

// ---- fused prepass ----
// blocks [0,512): Q scaled -> bf16 rows
// blocks [512,768): K -> fragment-ordered Kp[t][c][lane][8]
// blocks [768,1024): V -> fragment-ordered Vp[t][dt][h][lane][8]
__global__ __launch_bounds__(256) void fa_conv(const float* __restrict__ q,
                                               const float* __restrict__ k,
                                               const float* __restrict__ v,
                                               short* __restrict__ Qb,
                                               short* __restrict__ Kp,
                                               short* __restrict__ Vp) {
    int bid = blockIdx.x, tid = threadIdx.x;
    if (bid < 512) {
        int i = (bid * 256 + tid) * 4;
        float4 a = *(const float4*)(q + i);
        unsigned lo = cvt_pk_bf16(a.x * QSCALE, a.y * QSCALE);
        unsigned hi = cvt_pk_bf16(a.z * QSCALE, a.w * QSCALE);
        unsigned long long u = (unsigned long long)lo | ((unsigned long long)hi << 32);
        *(unsigned long long*)(Qb + i) = u;
    } else if (bid < 768) {
        int t = bid - 512;
        int c = tid >> 6, l = tid & 63, ql = l & 31, hi = l >> 5;
        const float* src = k + (size_t)(t * 32 + ql) * D + c * 16 + hi * 8;
        float4 a = *(const float4*)(src);
        float4 b = *(const float4*)(src + 4);
        uint4 u = { cvt_pk_bf16(a.x, a.y), cvt_pk_bf16(a.z, a.w),
                    cvt_pk_bf16(b.x, b.y), cvt_pk_bf16(b.z, b.w) };
        *(uint4*)(Kp + (size_t)t * 2048 + c * 512 + l * 8) = u;
    } else {
        int t = bid - 768;
        int dt = tid >> 7, h = (tid >> 6) & 1, hi = (tid >> 5) & 1, ql = tid & 31;
        const float* src = v + (size_t)(t * 32 + h * 16 + hi * 8) * D + dt * 32 + ql;
        float f[8];
#pragma unroll
        for (int j = 0; j < 8; ++j) f[j] = src[(size_t)j * D];
        uint4 u = { cvt_pk_bf16(f[0], f[1]), cvt_pk_bf16(f[2], f[3]),
                    cvt_pk_bf16(f[4], f[5]), cvt_pk_bf16(f[6], f[7]) };
        *(uint4*)(Vp + (size_t)t * 2048 + dt * 1024 + h * 512 + hi * 256 + ql * 8) = u;
    }
}

// ---- main: 32x32 swapped-operand FA partials ----
// No LDS, no barriers. K register-double-buffered one tile ahead; V loaded at
// tile start, consumed at PV. All repacks via bit_cast (registers, no scratch).
__global__ __launch_bounds__(256) void fa_part_kernel(const short* __restrict__ Qb,
                                                      const short* __restrict__ Kp,
                                                      const short* __restrict__ Vp,
                                                      short* __restrict__ OTb,
                                                      float* __restrict__ Ml,
                                                      int KN) {
    const int qt = blockIdx.x & 63;
    const int s  = blockIdx.x >> 6;
    const int w = threadIdx.x >> 6, lane = threadIdx.x & 63;
    const int ql = lane & 31, hi = lane >> 5;
    const int qrow = qt * 128 + w * 32 + ql;

    const short* qp = Qb + (size_t)qrow * D + hi * 8;
    short8 qf0 = *(const short8*)(qp);
    short8 qf1 = *(const short8*)(qp + 16);
    short8 qf2 = *(const short8*)(qp + 32);
    short8 qf3 = *(const short8*)(qp + 48);

    f32x16 acc0 = {}, acc1 = {};
    float mex = -INFINITY, lsum = 0.f;

    const int t0 = (s * KN) >> 5, nt = KN >> 5;   // 32-key tiles
    const short* kbp = Kp + (size_t)t0 * 2048 + lane * 8;
    const short* vbp = Vp + (size_t)t0 * 2048 + lane * 8;

    short8 kA0, kA1, kA2, kA3, kB0, kB1, kB2, kB3;
    short8 vf0, vf1, vf2, vf3;

#define LOADK(d0, d1, d2, d3, tt) do {                                     \
        const short* p_ = kbp + (size_t)(tt) * 2048;                       \
        d0 = *(const short8*)(p_);                                         \
        d1 = *(const short8*)(p_ + 512);                                   \
        d2 = *(const short8*)(p_ + 1024);                                  \
        d3 = *(const short8*)(p_ + 1536);                                  \
    } while (0)
#define LOADV(tt) do {                                                     \
        const short* p_ = vbp + (size_t)(tt) * 2048;                       \
        vf0 = *(const short8*)(p_);                                        \
        vf1 = *(const short8*)(p_ + 512);                                  \
        vf2 = *(const short8*)(p_ + 1024);                                 \
        vf3 = *(const short8*)(p_ + 1536);                                 \
    } while (0)

    // One 32-key tile: QK^T -> max3 tree -> exp2+pack+rowsum -> permlane -> PV
#define TILE(K0, K1, K2, K3) do {                                           \
        __builtin_amdgcn_s_setprio(1);                                      \
        f32x16 st = {};                                                     \
        st = __builtin_amdgcn_mfma_f32_32x32x16_bf16(K0, qf0, st, 0, 0, 0); \
        st = __builtin_amdgcn_mfma_f32_32x32x16_bf16(K1, qf1, st, 0, 0, 0); \
        st = __builtin_amdgcn_mfma_f32_32x32x16_bf16(K2, qf2, st, 0, 0, 0); \
        st = __builtin_amdgcn_mfma_f32_32x32x16_bf16(K3, qf3, st, 0, 0, 0); \
        __builtin_amdgcn_s_setprio(0);                                      \
        float m0_ = max3f(st[0], st[1], st[2]);                             \
        float m1_ = max3f(st[3], st[4], st[5]);                             \
        float m2_ = max3f(st[6], st[7], st[8]);                             \
        float m3_ = max3f(st[9], st[10], st[11]);                           \
        float m4_ = max3f(st[12], st[13], st[14]);                          \
        mex = max3f(mex, max3f(m0_, m1_, m2_), max3f(m3_, m4_, st[15]));    \
        unsigned pk0, pk1, pk2, pk3, pk4, pk5, pk6, pk7;                    \
        float rs_;                                                          \
        {                                                                   \
            float a_, b_;                                                   \
            a_ = __builtin_amdgcn_exp2f(st[0]);  b_ = __builtin_amdgcn_exp2f(st[1]);  \
            rs_ = a_ + b_;         pk0 = cvt_pk_bf16(a_, b_);               \
            a_ = __builtin_amdgcn_exp2f(st[2]);  b_ = __builtin_amdgcn_exp2f(st[3]);  \
            rs_ += a_ + b_;        pk1 = cvt_pk_bf16(a_, b_);               \
            a_ = __builtin_amdgcn_exp2f(st[4]);  b_ = __builtin_amdgcn_exp2f(st[5]);  \
            rs_ += a_ + b_;        pk2 = cvt_pk_bf16(a_, b_);               \
            a_ = __builtin_amdgcn_exp2f(st[6]);  b_ = __builtin_amdgcn_exp2f(st[7]);  \
            rs_ += a_ + b_;        pk3 = cvt_pk_bf16(a_, b_);               \
            a_ = __builtin_amdgcn_exp2f(st[8]);  b_ = __builtin_amdgcn_exp2f(st[9]);  \
            rs_ += a_ + b_;        pk4 = cvt_pk_bf16(a_, b_);               \
            a_ = __builtin_amdgcn_exp2f(st[10]); b_ = __builtin_amdgcn_exp2f(st[11]); \
            rs_ += a_ + b_;        pk5 = cvt_pk_bf16(a_, b_);               \
            a_ = __builtin_amdgcn_exp2f(st[12]); b_ = __builtin_amdgcn_exp2f(st[13]); \
            rs_ += a_ + b_;        pk6 = cvt_pk_bf16(a_, b_);               \
            a_ = __builtin_amdgcn_exp2f(st[14]); b_ = __builtin_amdgcn_exp2f(st[15]); \
            rs_ += a_ + b_;        pk7 = cvt_pk_bf16(a_, b_);               \
        }                                                                   \
        lsum += rs_;                                                        \
        auto r0_ = __builtin_amdgcn_permlane32_swap((int)pk0, (int)pk2, false, false); \
        auto r1_ = __builtin_amdgcn_permlane32_swap((int)pk1, (int)pk3, false, false); \
        auto r2_ = __builtin_amdgcn_permlane32_swap((int)pk4, (int)pk6, false, false); \
        auto r3_ = __builtin_amdgcn_permlane32_swap((int)pk5, (int)pk7, false, false); \
        ui4 va_ = { (unsigned)r0_[0], (unsigned)r1_[0],                     \
                    (unsigned)r0_[1], (unsigned)r1_[1] };                   \
        ui4 vb_ = { (unsigned)r2_[0], (unsigned)r3_[0],                     \
                    (unsigned)r2_[1], (unsigned)r3_[1] };                   \
        short8 pb0 = __builtin_bit_cast(short8, va_);                       \
        short8 pb1 = __builtin_bit_cast(short8, vb_);                       \
        __builtin_amdgcn_s_setprio(1);                                      \
        acc0 = __builtin_amdgcn_mfma_f32_32x32x16_bf16(vf0, pb0, acc0, 0, 0, 0); \
        acc0 = __builtin_amdgcn_mfma_f32_32x32x16_bf16(vf1, pb1, acc0, 0, 0, 0); \
        acc1 = __builtin_amdgcn_mfma_f32_32x32x16_bf16(vf2, pb0, acc1, 0, 0, 0); \
        acc1 = __builtin_amdgcn_mfma_f32_32x32x16_bf16(vf3, pb1, acc1, 0, 0, 0); \
        __builtin_amdgcn_s_setprio(0);                                      \
    } while (0)

    LOADK(kA0, kA1, kA2, kA3, 0);
#pragma unroll 1
    for (int T = 0; T < nt; T += 2) {
        LOADV(T);                                   // V for tile T
        LOADK(kB0, kB1, kB2, kB3, T + 1);           // K one tile ahead
        TILE(kA0, kA1, kA2, kA3);
        LOADV(T + 1);                               // V for tile T+1
        if (T + 2 < nt) LOADK(kA0, kA1, kA2, kA3, T + 2);
        TILE(kB0, kB1, kB2, kB3);
    }
#undef LOADK
#undef LOADV
#undef TILE

    // cross-half reductions (lane's 16 k-rows + partner's 16 = full 32 per q)
    mex = fmaxf(mex, __shfl_xor(mex, 32));
    lsum += __shfl_xor(lsum, 32);

    // write O^T partials (bf16): OTb[s*64+d][qrow]
#pragma unroll
    for (int r = 0; r < 16; ++r) {
        int d0 = (r & 3) + 8 * (r >> 2) + 4 * hi;
        OTb[(size_t)(s * 64 + d0) * N + qrow]      = f32_to_bf16_bits(acc0[r]);
        OTb[(size_t)(s * 64 + 32 + d0) * N + qrow] = f32_to_bf16_bits(acc1[r]);
    }
    if (hi == 0) {
        Ml[(size_t)(s * 2 + 0) * N + qrow] = lsum;
        Ml[(size_t)(s * 2 + 1) * N + qrow] = mex;
    }
}

// ---- combine: plain sum of partials, L = exp2(-mg)*sum(l) ----
__global__ __launch_bounds__(256) void fa_comb_kernel(const short* __restrict__ OTb,
                                                      const float* __restrict__ Ml,
                                                      float* __restrict__ Out, int S) {
    const int r0 = blockIdx.x * 64;
    const int row = threadIdx.x & 63, db = threadIdx.x >> 6;
    const int grow = r0 + row;

    float v[16];
#pragma unroll
    for (int i = 0; i < 16; ++i) v[i] = 0.f;
    float L = 0.f, mg = -INFINITY;
    for (int s = 0; s < S; ++s) {
#pragma unroll
        for (int i = 0; i < 16; ++i)
            v[i] += bfbits_to_f32((unsigned short)OTb[(size_t)(s * 64 + db * 16 + i) * N + grow]);
        L  += Ml[(size_t)(s * 2 + 0) * N + grow];
        mg = fmaxf(mg, Ml[(size_t)(s * 2 + 1) * N + grow]);
    }
    float inv = 1.0f / L;
    float4* outv = (float4*)(Out + (size_t)grow * D + db * 16);
#pragma unroll
    for (int i4 = 0; i4 < 4; ++i4) {
        float4 o = { v[i4 * 4 + 0] * inv, v[i4 * 4 + 1] * inv,
                     v[i4 * 4 + 2] * inv, v[i4 * 4 + 3] * inv };
        outv[i4] = o;
    }
    if (db == 0) Out[(size_t)N * D + grow] = exp2f(-mg) * L;
}

extern "C" void kernel_launch(void* const* d_in, const int* in_sizes, int n_in,
                              void* d_out, int out_size, void* d_ws, size_t ws_size,
                              hipStream_t stream) {
    const float* q = (const float*)d_in[0];
    const float* k = (const float*)d_in[1];
    const float* v = (const float*)d_in[2];
    float* out = (float*)d_out;

    short* Qb = (short*)d_ws;                         // 1 MB
    short* Kp = Qb + (size_t)N * D;                   // 1 MB
    short* Vp = Kp + (size_t)N * D;                   // 1 MB
    short* OTb = (short*)((char*)d_ws + 3 * 1048576); // S*64*N bf16

    int S = 16;
    while (S > 1 &&
           3ull * 1048576 + (size_t)S * (64ull * N * 2) + (size_t)S * (2ull * N * 4) > ws_size)
        S >>= 1;
    float* Ml = (float*)(OTb + (size_t)S * 64 * N);
    int KN = N / S;

    fa_conv<<<1024, 256, 0, stream>>>(q, k, v, Qb, Kp, Vp);
    fa_part_kernel<<<64 * S, 256, 0, stream>>>(Qb, Kp, Vp, OTb, Ml, KN);
    fa_comb_kernel<<<N / 64, 256, 0, stream>>>(OTb, Ml, out, S);
}

// Round 12
// 47.121 us; speedup vs baseline: 4.7826x; 1.0089x over previous
//
#include <hip/hip_runtime.h>
#include <hip/hip_bf16.h>
#include <math.h>

#define N 8192
#define D 64
// fold (1/sqrt(D)) * log2(e) into Q so S2 = Qs·K is in base-2 units
#define QSCALE 0.18033688011112042f

typedef __attribute__((ext_vector_type(8))) short short8;
typedef __attribute__((ext_vector_type(16))) float f32x16;
typedef __attribute__((ext_vector_type(4))) unsigned int ui4;

__device__ inline short f32_to_bf16_bits(float x) {
    unsigned u = __builtin_bit_cast(unsigned, x);
    u += 0x7FFFu + ((u >> 16) & 1u);   // RNE
    return (short)(u >> 16);
}
__device__ inline float bfbits_to_f32(unsigned short u) {
    return __builtin_bit_cast(float, ((unsigned)u) << 16);
}
// v_cvt_pk_bf16_f32: packs two f32 -> two bf16 (RNE) in one VALU op.
__device__ inline unsigned cvt_pk_bf16(float a, float b) {
    unsigned r;
    asm("v_cvt_pk_bf16_f32 %0, %1, %2" : "=v"(r) : "v"(a), "v"(b));
    return r;
}
__device__ inline float max3f(float a, float b, float c) {
    float d;
    asm("v_max3_f32 %0, %1, %2, %3" : "=v"(d) : "v"(a), "v"(b), "v"(c));
    return d;
}

// ---- fused prepass ----
// blocks [0,512): Q scaled -> bf16 rows
// blocks [512,768): K -> fragment-ordered Kp[t][c][lane][8]
// blocks [768,1024): V -> kappa-reordered fragment order Vp[t][dt][h][lane][8]
//   PV B-operand (P) arrives in S^T's natural layout: k-slot (hi,j) holds key
//   (j&3) + 8*(j>>2) + 4*hi (kappa = swap bits 2<->3). V rows are stored in the
//   SAME kappa order so the contraction pairs matching keys -> no permlane.
__global__ __launch_bounds__(256) void fa_conv(const float* __restrict__ q,
                                               const float* __restrict__ k,
                                               const float* __restrict__ v,
                                               short* __restrict__ Qb,
                                               short* __restrict__ Kp,
                                               short* __restrict__ Vp) {
    int bid = blockIdx.x, tid = threadIdx.x;
    if (bid < 512) {
        int i = (bid * 256 + tid) * 4;
        float4 a = *(const float4*)(q + i);
        unsigned lo = cvt_pk_bf16(a.x * QSCALE, a.y * QSCALE);
        unsigned hi = cvt_pk_bf16(a.z * QSCALE, a.w * QSCALE);
        unsigned long long u = (unsigned long long)lo | ((unsigned long long)hi << 32);
        *(unsigned long long*)(Qb + i) = u;
    } else if (bid < 768) {
        int t = bid - 512;
        int c = tid >> 6, l = tid & 63, ql = l & 31, hi = l >> 5;
        const float* src = k + (size_t)(t * 32 + ql) * D + c * 16 + hi * 8;
        float4 a = *(const float4*)(src);
        float4 b = *(const float4*)(src + 4);
        uint4 u = { cvt_pk_bf16(a.x, a.y), cvt_pk_bf16(a.z, a.w),
                    cvt_pk_bf16(b.x, b.y), cvt_pk_bf16(b.z, b.w) };
        *(uint4*)(Kp + (size_t)t * 2048 + c * 512 + l * 8) = u;
    } else {
        int t = bid - 768;
        int dt = tid >> 7, h = (tid >> 6) & 1, hi = (tid >> 5) & 1, ql = tid & 31;
        // kappa-reordered: slot j holds V[key t*32 + h*16 + 4*hi + (j&3) + 8*(j>>2)]
        const float* src = v + (size_t)(t * 32 + h * 16 + hi * 4) * D + dt * 32 + ql;
        float f[8];
#pragma unroll
        for (int j = 0; j < 8; ++j)
            f[j] = src[(size_t)((j & 3) + 8 * (j >> 2)) * D];
        uint4 u = { cvt_pk_bf16(f[0], f[1]), cvt_pk_bf16(f[2], f[3]),
                    cvt_pk_bf16(f[4], f[5]), cvt_pk_bf16(f[6], f[7]) };
        *(uint4*)(Vp + (size_t)t * 2048 + dt * 1024 + h * 512 + hi * 256 + ql * 8) = u;
    }
}

// ---- main: 32x32 swapped-operand FA partials, zero cross-lane softmax->PV ----
__global__ __launch_bounds__(256) void fa_part_kernel(const short* __restrict__ Qb,
                                                      const short* __restrict__ Kp,
                                                      const short* __restrict__ Vp,
                                                      short* __restrict__ OTb,
                                                      float* __restrict__ Ml,
                                                      int KN) {
    const int qt = blockIdx.x & 63;
    const int s  = blockIdx.x >> 6;
    const int w = threadIdx.x >> 6, lane = threadIdx.x & 63;
    const int ql = lane & 31, hi = lane >> 5;
    const int qrow = qt * 128 + w * 32 + ql;

    const short* qp = Qb + (size_t)qrow * D + hi * 8;
    short8 qf0 = *(const short8*)(qp);
    short8 qf1 = *(const short8*)(qp + 16);
    short8 qf2 = *(const short8*)(qp + 32);
    short8 qf3 = *(const short8*)(qp + 48);

    f32x16 acc0 = {}, acc1 = {};
    float mex = -INFINITY, lsum = 0.f;

    const int t0 = (s * KN) >> 5, nt = KN >> 5;   // 32-key tiles
    const short* kp = Kp + (size_t)t0 * 2048 + lane * 8;
    const short* vp = Vp + (size_t)t0 * 2048 + lane * 8;

    short8 kA0, kA1, kA2, kA3, kB0, kB1, kB2, kB3;
    short8 vf0, vf1, vf2, vf3;

#define LOADK(d0, d1, d2, d3) do {                                         \
        d0 = *(const short8*)(kp);                                         \
        d1 = *(const short8*)(kp + 512);                                   \
        d2 = *(const short8*)(kp + 1024);                                  \
        d3 = *(const short8*)(kp + 1536);                                  \
        kp += 2048;                                                        \
    } while (0)
#define LOADV() do {                                                       \
        vf0 = *(const short8*)(vp);                                        \
        vf1 = *(const short8*)(vp + 512);                                  \
        vf2 = *(const short8*)(vp + 1024);                                 \
        vf3 = *(const short8*)(vp + 1536);                                 \
        vp += 2048;                                                        \
    } while (0)

    // One 32-key tile: QK^T -> max3 tree -> exp2+pack+rowsum -> PV (no shuffles)
#define TILE(K0, K1, K2, K3) do {                                           \
        __builtin_amdgcn_s_setprio(1);                                      \
        f32x16 st = {};                                                     \
        st = __builtin_amdgcn_mfma_f32_32x32x16_bf16(K0, qf0, st, 0, 0, 0); \
        st = __builtin_amdgcn_mfma_f32_32x32x16_bf16(K1, qf1, st, 0, 0, 0); \
        st = __builtin_amdgcn_mfma_f32_32x32x16_bf16(K2, qf2, st, 0, 0, 0); \
        st = __builtin_amdgcn_mfma_f32_32x32x16_bf16(K3, qf3, st, 0, 0, 0); \
        __builtin_amdgcn_s_setprio(0);                                      \
        float m0_ = max3f(st[0], st[1], st[2]);                             \
        float m1_ = max3f(st[3], st[4], st[5]);                             \
        float m2_ = max3f(st[6], st[7], st[8]);                             \
        float m3_ = max3f(st[9], st[10], st[11]);                           \
        float m4_ = max3f(st[12], st[13], st[14]);                          \
        mex = max3f(mex, max3f(m0_, m1_, m2_), max3f(m3_, m4_, st[15]));    \
        unsigned pk0, pk1, pk2, pk3, pk4, pk5, pk6, pk7;                    \
        float rs_;                                                          \
        {                                                                   \
            float a_, b_;                                                   \
            a_ = __builtin_amdgcn_exp2f(st[0]);  b_ = __builtin_amdgcn_exp2f(st[1]);  \
            rs_ = a_ + b_;         pk0 = cvt_pk_bf16(a_, b_);               \
            a_ = __builtin_amdgcn_exp2f(st[2]);  b_ = __builtin_amdgcn_exp2f(st[3]);  \
            rs_ += a_ + b_;        pk1 = cvt_pk_bf16(a_, b_);               \
            a_ = __builtin_amdgcn_exp2f(st[4]);  b_ = __builtin_amdgcn_exp2f(st[5]);  \
            rs_ += a_ + b_;        pk2 = cvt_pk_bf16(a_, b_);               \
            a_ = __builtin_amdgcn_exp2f(st[6]);  b_ = __builtin_amdgcn_exp2f(st[7]);  \
            rs_ += a_ + b_;        pk3 = cvt_pk_bf16(a_, b_);               \
            a_ = __builtin_amdgcn_exp2f(st[8]);  b_ = __builtin_amdgcn_exp2f(st[9]);  \
            rs_ += a_ + b_;        pk4 = cvt_pk_bf16(a_, b_);               \
            a_ = __builtin_amdgcn_exp2f(st[10]); b_ = __builtin_amdgcn_exp2f(st[11]); \
            rs_ += a_ + b_;        pk5 = cvt_pk_bf16(a_, b_);               \
            a_ = __builtin_amdgcn_exp2f(st[12]); b_ = __builtin_amdgcn_exp2f(st[13]); \
            rs_ += a_ + b_;        pk6 = cvt_pk_bf16(a_, b_);               \
            a_ = __builtin_amdgcn_exp2f(st[14]); b_ = __builtin_amdgcn_exp2f(st[15]); \
            rs_ += a_ + b_;        pk7 = cvt_pk_bf16(a_, b_);               \
        }                                                                   \
        lsum += rs_;                                                        \
        ui4 va_ = { pk0, pk1, pk2, pk3 };                                   \
        ui4 vb_ = { pk4, pk5, pk6, pk7 };                                   \
        short8 pb0 = __builtin_bit_cast(short8, va_);                       \
        short8 pb1 = __builtin_bit_cast(short8, vb_);                       \
        __builtin_amdgcn_s_setprio(1);                                      \
        acc0 = __builtin_amdgcn_mfma_f32_32x32x16_bf16(vf0, pb0, acc0, 0, 0, 0); \
        acc0 = __builtin_amdgcn_mfma_f32_32x32x16_bf16(vf1, pb1, acc0, 0, 0, 0); \
        acc1 = __builtin_amdgcn_mfma_f32_32x32x16_bf16(vf2, pb0, acc1, 0, 0, 0); \
        acc1 = __builtin_amdgcn_mfma_f32_32x32x16_bf16(vf3, pb1, acc1, 0, 0, 0); \
        __builtin_amdgcn_s_setprio(0);                                      \
    } while (0)

    LOADK(kA0, kA1, kA2, kA3);
#pragma unroll 1
    for (int T = 0; T < nt; T += 2) {
        LOADV();                                    // V for tile T
        LOADK(kB0, kB1, kB2, kB3);                  // K one tile ahead
        TILE(kA0, kA1, kA2, kA3);
        LOADV();                                    // V for tile T+1
        if (T + 2 < nt) LOADK(kA0, kA1, kA2, kA3);
        TILE(kB0, kB1, kB2, kB3);
    }
#undef LOADK
#undef LOADV
#undef TILE

    // cross-half reductions (lane's 16 k-rows + partner's 16 = full 32 per q)
    mex = fmaxf(mex, __shfl_xor(mex, 32));
    lsum += __shfl_xor(lsum, 32);

    // write O^T partials (bf16): OTb[s*64+d][qrow]
#pragma unroll
    for (int r = 0; r < 16; ++r) {
        int d0 = (r & 3) + 8 * (r >> 2) + 4 * hi;
        OTb[(size_t)(s * 64 + d0) * N + qrow]      = f32_to_bf16_bits(acc0[r]);
        OTb[(size_t)(s * 64 + 32 + d0) * N + qrow] = f32_to_bf16_bits(acc1[r]);
    }
    if (hi == 0) {
        Ml[(size_t)(s * 2 + 0) * N + qrow] = lsum;
        Ml[(size_t)(s * 2 + 1) * N + qrow] = mex;
    }
}

// ---- combine: plain sum of partials, L = exp2(-mg)*sum(l) ----
__global__ __launch_bounds__(256) void fa_comb_kernel(const short* __restrict__ OTb,
                                                      const float* __restrict__ Ml,
                                                      float* __restrict__ Out, int S) {
    const int r0 = blockIdx.x * 64;
    const int row = threadIdx.x & 63, db = threadIdx.x >> 6;
    const int grow = r0 + row;

    float v[16];
#pragma unroll
    for (int i = 0; i < 16; ++i) v[i] = 0.f;
    float L = 0.f, mg = -INFINITY;
    for (int s = 0; s < S; ++s) {
#pragma unroll
        for (int i = 0; i < 16; ++i)
            v[i] += bfbits_to_f32((unsigned short)OTb[(size_t)(s * 64 + db * 16 + i) * N + grow]);
        L  += Ml[(size_t)(s * 2 + 0) * N + grow];
        mg = fmaxf(mg, Ml[(size_t)(s * 2 + 1) * N + grow]);
    }
    float inv = 1.0f / L;
    float4* outv = (float4*)(Out + (size_t)grow * D + db * 16);
#pragma unroll
    for (int i4 = 0; i4 < 4; ++i4) {
        float4 o = { v[i4 * 4 + 0] * inv, v[i4 * 4 + 1] * inv,
                     v[i4 * 4 + 2] * inv, v[i4 * 4 + 3] * inv };
        outv[i4] = o;
    }
    if (db == 0) Out[(size_t)N * D + grow] = exp2f(-mg) * L;
}

extern "C" void kernel_launch(void* const* d_in, const int* in_sizes, int n_in,
                              void* d_out, int out_size, void* d_ws, size_t ws_size,
                              hipStream_t stream) {
    const float* q = (const float*)d_in[0];
    const float* k = (const float*)d_in[1];
    const float* v = (const float*)d_in[2];
    float* out = (float*)d_out;

    short* Qb = (short*)d_ws;                         // 1 MB
    short* Kp = Qb + (size_t)N * D;                   // 1 MB
    short* Vp = Kp + (size_t)N * D;                   // 1 MB
    short* OTb = (short*)((char*)d_ws + 3 * 1048576); // S*64*N bf16

    int S = 16;
    while (S > 1 &&
           3ull * 1048576 + (size_t)S * (64ull * N * 2) + (size_t)S * (2ull * N * 4) > ws_size)
        S >>= 1;
    float* Ml = (float*)(OTb + (size_t)S * 64 * N);
    int KN = N / S;

    fa_conv<<<1024, 256, 0, stream>>>(q, k, v, Qb, Kp, Vp);
    fa_part_kernel<<<64 * S, 256, 0, stream>>>(Qb, Kp, Vp, OTb, Ml, KN);
    fa_comb_kernel<<<N / 64, 256, 0, stream>>>(OTb, Ml, out, S);
}